// Round 3
// baseline (49.691 us; speedup 1.0000x reference)
//
#include <hip/hip_runtime.h>
#include <cstdint>

typedef unsigned long long u64;
typedef unsigned int u32;

#define BB 64
#define DD 128
#define OO 512
#define II 512
#define OT 64   // o-tile per compute block

#define XROWS (BB * DD)          // 8192 x-rows (b,d)
#define WROWS (DD * OO)          // 65536 w-rows (d,o)
#define NROWS (XROWS + WROWS)    // 73728
#define XWORDS (XROWS * 8)       // u64 words in packed x region

// ---------------------------------------------------------------------------
// Input-format detection (uniform address -> compiles to scalar loads).
// mode 0: raw bytes {0,1} | mode 1: int32 {0,1} | mode 2: float32 {0.f,1.f}
// 32 sampled u32 words: misdetection prob <= 8^-32 for random binary data.
// ---------------------------------------------------------------------------
__device__ __forceinline__ int detect_mode(const u32* __restrict__ w) {
    bool all01 = true, allf = true;
#pragma unroll
    for (int i = 0; i < 32; ++i) {
        u32 v = w[i];
        all01 = all01 && (v <= 1u);
        allf  = allf  && (v == 0u || v == 0x3F800000u);
    }
    return all01 ? 1 : (allf ? 2 : 0);
}

// ---------------------------------------------------------------------------
// Pack kernel: one wave per 512-element row. Lane L loads elements
// [8L, 8L+8) -- lane-adjacent, fully coalesced (1-2 KB per wave-instr).
// 8 ballots produce the row's 8 packed u64 words. Bit order: word j holds
// elements {8L+j : L in 0..63} -- permuted, but identical for x and w rows,
// so popcount(xor) over all 8 words still counts all 512 positions.
// Packed row index == global wave id (x rows 0..8191, then w rows).
// ---------------------------------------------------------------------------
__global__ __launch_bounds__(256)
void pack_kernel(const void* __restrict__ x, const void* __restrict__ w,
                 u64* __restrict__ packed) {
    const int gtid = blockIdx.x * 256 + threadIdx.x;
    const int wave = gtid >> 6;          // 0..NROWS-1, grid sized exactly
    const int lane = threadIdx.x & 63;

    const int mode = detect_mode((const u32*)w);

    const void* src;
    size_t elem0;
    if (wave < XROWS) { src = x; elem0 = (size_t)wave * II; }
    else              { src = w; elem0 = (size_t)(wave - XROWS) * II; }

    u32 e[8];
    if (mode == 0) {
        u64 v = *(const u64*)((const uint8_t*)src + elem0 + (size_t)lane * 8);
#pragma unroll
        for (int j = 0; j < 8; ++j) e[j] = (u32)(v >> (8 * j)) & 1u;
    } else if (mode == 1) {
        const uint4* s = (const uint4*)((const u32*)src + elem0 + (size_t)lane * 8);
        uint4 a = s[0], b = s[1];
        e[0] = a.x & 1u; e[1] = a.y & 1u; e[2] = a.z & 1u; e[3] = a.w & 1u;
        e[4] = b.x & 1u; e[5] = b.y & 1u; e[6] = b.z & 1u; e[7] = b.w & 1u;
    } else {
        const uint4* s = (const uint4*)((const u32*)src + elem0 + (size_t)lane * 8);
        uint4 a = s[0], b = s[1];
        e[0] = (a.x >> 23) & 1u; e[1] = (a.y >> 23) & 1u;
        e[2] = (a.z >> 23) & 1u; e[3] = (a.w >> 23) & 1u;
        e[4] = (b.x >> 23) & 1u; e[5] = (b.y >> 23) & 1u;
        e[6] = (b.z >> 23) & 1u; e[7] = (b.w >> 23) & 1u;
    }

    u64 my = 0;
#pragma unroll
    for (int j = 0; j < 8; ++j) {
        u64 bj = __ballot(e[j]);          // wave-uniform packed word j
        if (lane == j) my = bj;           // lane j will store word j
    }
    u64* dst = packed + (size_t)wave * 8;
    if (lane < 8) dst[lane] = my;         // 64B contiguous store per row
}

// ---------------------------------------------------------------------------
// Compute kernel: block = (d, 64-wide o-tile). Reads packed bits from ws.
// Thread owns o = tid&63, b-range (tid>>6)*16..+15.
// matches = 512 - popcount(x ^ w); out = (matches > bias) as int32.
// ---------------------------------------------------------------------------
__global__ __launch_bounds__(256)
void compute_kernel(const u64* __restrict__ packed,
                    const float* __restrict__ bias, int* __restrict__ out) {
    __shared__ u64 xp[BB][8];   // broadcast reads in Phase C -> no conflicts
    __shared__ u64 wp[OT][9];   // +1 pad: one-time strided read <=4-way

    const int tid = threadIdx.x;
    const int blk = blockIdx.x;
    const int d   = blk >> 3;            // 8 o-tiles per d
    const int o0  = (blk & 7) * OT;

    // w tile: rows XROWS + d*OO + (o0..o0+63); contiguous 4 KB in packed buf
#pragma unroll
    for (int t = tid; t < OT * 8; t += 256) {
        int o = t >> 3, k = t & 7;
        wp[o][k] = packed[(size_t)(XROWS + d * OO + o0 + o) * 8 + k];
    }
    // x tile: rows b*DD + d for b=0..63 (64B contiguous per row)
#pragma unroll
    for (int t = tid; t < BB * 8; t += 256) {
        int b = t >> 3, k = t & 7;
        xp[b][k] = packed[(size_t)(b * DD + d) * 8 + k];
    }
    __syncthreads();

    const int o  = tid & 63;
    const int b0 = (tid >> 6) * 16;

    u64 wr[8];
#pragma unroll
    for (int k = 0; k < 8; ++k) wr[k] = wp[o][k];
    const float bv = bias[d * OO + o0 + o];

    int* outp = out + (size_t)d * OO + o0 + o;
#pragma unroll 4
    for (int bi = 0; bi < 16; ++bi) {
        const int b = b0 + bi;
        int m = 0;
#pragma unroll
        for (int k = 0; k < 8; ++k) m += __popcll(xp[b][k] ^ wr[k]);
        const float act = (float)(512 - m);   // exact integer in fp32
        outp[(size_t)b * (DD * OO)] = (act > bv) ? 1 : 0;
    }
}

extern "C" void kernel_launch(void* const* d_in, const int* in_sizes, int n_in,
                              void* d_out, int out_size, void* d_ws, size_t ws_size,
                              hipStream_t stream) {
    const void*  x    = d_in[0];                 // (B, D, I) binary
    const void*  w    = d_in[1];                 // (D, O, I) binary
    const float* bias = (const float*)d_in[2];   // (D, O) f32
    int*         out  = (int*)d_out;             // (B, D, O) bool as int32
    u64*         pk   = (u64*)d_ws;              // 4.5 MB packed bits

    // Pack: one wave per row, NROWS waves total -> NROWS/4 blocks of 256.
    pack_kernel<<<NROWS / 4, 256, 0, stream>>>(x, w, pk);
    // Compute: 1024 blocks (128 d x 8 o-tiles).
    compute_kernel<<<DD * (OO / OT), 256, 0, stream>>>(pk, bias, out);
}

// Round 4
// 39.195 us; speedup vs baseline: 1.2678x; 1.2678x over previous
//
#include <hip/hip_runtime.h>
#include <cstdint>

typedef unsigned long long u64;
typedef unsigned int u32;

#define BB 64
#define DD 128
#define OO 512
#define II 512
#define OT 64              // o-tile per compute block
#define XROWS (BB * DD)    // 8192 packed x rows

// ---------------------------------------------------------------------------
// Input-format detection (uniform -> scalar loads, same result every wave).
// mode 0: raw bytes {0,1} | mode 1: int32 {0,1} | mode 2: float32 {0.f,1.f}
// Byte data seen as u32 has multi-byte patterns > 1 -> falls through to 0.
// Misdetection prob for 32 random binary words is astronomically small.
// ---------------------------------------------------------------------------
__device__ __forceinline__ int detect_mode(const u32* __restrict__ w) {
    bool all01 = true, allf = true;
#pragma unroll
    for (int i = 0; i < 32; ++i) {
        u32 v = w[i];
        all01 = all01 && (v <= 1u);
        allf  = allf  && (v == 0u || v == 0x3F800000u);
    }
    return all01 ? 1 : (allf ? 2 : 0);
}

// ---------------------------------------------------------------------------
// Wave-cooperatively pack one 512-element binary row into 8 u64 words.
// Loads are lane-adjacent (mode 0: 8B/lane = 512B/instr; mode 1/2: one
// dwordx4 = 1KB contiguous fully-used per instr). 8 ballots produce the
// packed words. The bit mapping i -> position is a fixed bijection used
// identically for x and w rows, so popcount(xor) counts mismatches exactly.
// Returns the word this lane stores (valid for lane < 8).
// ---------------------------------------------------------------------------
__device__ __forceinline__ u64 pack_row(const void* __restrict__ src,
                                        size_t elem0, int mode, int lane) {
    u64 my = 0;
    if (mode == 0) {
        u64 v = *(const u64*)((const uint8_t*)src + elem0 + (size_t)lane * 8);
#pragma unroll
        for (int j = 0; j < 8; ++j) {
            u64 bj = __ballot(((u32)(v >> (8 * j))) & 1u);
            if (lane == j) my = bj;
        }
    } else {
        const u32 sh = (mode == 1) ? 0u : 23u;   // int32: bit0; float: bit23
        const uint4* p = (const uint4*)((const u32*)src + elem0);
        uint4 v0 = p[lane];        // elems [4L, 4L+4)
        uint4 v1 = p[64 + lane];   // elems [256+4L, 256+4L+4)
        u32 b0 = (v0.x >> sh) & 1u, b1 = (v0.y >> sh) & 1u;
        u32 b2 = (v0.z >> sh) & 1u, b3 = (v0.w >> sh) & 1u;
        u32 b4 = (v1.x >> sh) & 1u, b5 = (v1.y >> sh) & 1u;
        u32 b6 = (v1.z >> sh) & 1u, b7 = (v1.w >> sh) & 1u;
        u64 w0 = __ballot(b0), w1 = __ballot(b1), w2 = __ballot(b2), w3 = __ballot(b3);
        u64 w4 = __ballot(b4), w5 = __ballot(b5), w6 = __ballot(b6), w7 = __ballot(b7);
        if (lane == 0) my = w0;  if (lane == 1) my = w1;
        if (lane == 2) my = w2;  if (lane == 3) my = w3;
        if (lane == 4) my = w4;  if (lane == 5) my = w5;
        if (lane == 6) my = w6;  if (lane == 7) my = w7;
    }
    return my;
}

// ---------------------------------------------------------------------------
// Kernel 1: pack x (B*D rows) into d_ws. 512 KB output, L2-resident.
// One wave per row.
// ---------------------------------------------------------------------------
__global__ __launch_bounds__(256)
void pack_x_kernel(const void* __restrict__ x, const void* __restrict__ w,
                   u64* __restrict__ packed) {
    const int gtid = blockIdx.x * 256 + threadIdx.x;
    const int row  = gtid >> 6;          // 0..XROWS-1 (grid sized exactly)
    const int lane = threadIdx.x & 63;
    const int mode = detect_mode((const u32*)w);
    u64 my = pack_row(x, (size_t)row * II, mode, lane);
    if (lane < 8) packed[(size_t)row * 8 + lane] = my;
}

// ---------------------------------------------------------------------------
// Kernel 2 (fused): block = (d, 64-wide o-tile). Each of 4 waves packs its
// 16 w rows straight from global (read exactly once, fully coalesced) into
// LDS; packed x tile comes from d_ws. Then thread owns o = tid&63 and 16 b's:
// matches = 512 - popcount(x ^ w); out = (matches > bias) as int32.
// ---------------------------------------------------------------------------
__global__ __launch_bounds__(256)
void fused_kernel(const void* __restrict__ w, const u64* __restrict__ px,
                  const float* __restrict__ bias, int* __restrict__ out) {
    __shared__ u64 wp[OT][9];   // +1 pad: strided one-time read <=4-way
    __shared__ u64 xp[BB][8];   // Phase-C reads are wave-broadcast

    const int tid  = threadIdx.x;
    const int blk  = blockIdx.x;
    const int d    = blk >> 3;           // 8 o-tiles per d
    const int o0   = (blk & 7) * OT;
    const int wv   = tid >> 6;
    const int lane = tid & 63;

    const int mode = detect_mode((const u32*)w);

    // Pack 16 w rows per wave: 2 dwordx4 loads (1KB each, fully used) + 8
    // ballots per row; unrolled so up to 32 loads are in flight.
#pragma unroll
    for (int r = 0; r < 16; ++r) {
        const int o = wv * 16 + r;
        u64 my = pack_row(w, ((size_t)(d * OO + o0 + o)) * II, mode, lane);
        if (lane < 8) wp[o][lane] = my;
    }
    // Packed x tile: 512 u64 / 256 threads = 2 each (64B per b-row, L2-hot).
#pragma unroll
    for (int t = tid; t < BB * 8; t += 256) {
        int b = t >> 3, k = t & 7;
        xp[b][k] = px[(size_t)(b * DD + d) * 8 + k];
    }
    const float bv = bias[d * OO + o0 + (tid & 63)];
    __syncthreads();

    const int o  = tid & 63;
    const int b0 = (tid >> 6) * 16;

    u64 wr[8];
#pragma unroll
    for (int k = 0; k < 8; ++k) wr[k] = wp[o][k];

    int* outp = out + (size_t)d * OO + o0 + o;
#pragma unroll 4
    for (int bi = 0; bi < 16; ++bi) {
        const int b = b0 + bi;
        int m = 0;
#pragma unroll
        for (int k = 0; k < 8; ++k) m += __popcll(xp[b][k] ^ wr[k]);
        const float act = (float)(512 - m);   // exact integer in fp32
        outp[(size_t)b * (DD * OO)] = (act > bv) ? 1 : 0;
    }
}

extern "C" void kernel_launch(void* const* d_in, const int* in_sizes, int n_in,
                              void* d_out, int out_size, void* d_ws, size_t ws_size,
                              hipStream_t stream) {
    const void*  x    = d_in[0];                 // (B, D, I) binary
    const void*  w    = d_in[1];                 // (D, O, I) binary
    const float* bias = (const float*)d_in[2];   // (D, O) f32
    int*         out  = (int*)d_out;             // (B, D, O) bool as int32
    u64*         px   = (u64*)d_ws;              // 512 KB packed x

    pack_x_kernel<<<XROWS / 4, 256, 0, stream>>>(x, w, px);
    fused_kernel<<<DD * (OO / OT), 256, 0, stream>>>(w, px, bias, out);
}